// Round 1
// baseline (4697.723 us; speedup 1.0000x reference)
//
#include <hip/hip_runtime.h>
#include <hip/hip_bf16.h>

#define BB 32
#define NN 128
#define TT 16
#define FN 16
#define FE 8
#define FG 8
#define FH 16
#define HH 128
#define DEC 64

// ws layout (floats):
// base_node [B*N*H]   @ 0
// We        [FE*H]    @ 524288      (W_enc_e @ W_me)
// mg        [B*H]     @ 525312      (graph_fts @ W_mg)
// m1p       [B*N*H]   @ 529408      (z@W_m1 + mg broadcast)
// m2        [B*N*H]   @ 1053696
// o1        [B*N*H]   @ 1577984
// hidden    [B*N*H]   @ 2102272
// total 2626560 floats = 10.5 MB

__global__ __launch_bounds__(HH) void prep1(const float* __restrict__ node,
                                            const float* __restrict__ Wn,
                                            float* __restrict__ base_node,
                                            float* __restrict__ hidden) {
    int row = blockIdx.x;       // b*N+i
    int h = threadIdx.x;
    float acc = 0.f;
#pragma unroll
    for (int f = 0; f < FN; ++f)
        acc += node[row * FN + f] * Wn[f * HH + h];
    base_node[row * HH + h] = acc;
    hidden[row * HH + h] = 0.f;
}

__global__ __launch_bounds__(HH) void prep2(const float* __restrict__ graph,
                                            const float* __restrict__ Wg,
                                            const float* __restrict__ Wmg,
                                            const float* __restrict__ Wee,
                                            const float* __restrict__ Wme,
                                            float* __restrict__ mg,
                                            float* __restrict__ We) {
    int h = threadIdx.x;
    if (blockIdx.x < BB) {
        int b = blockIdx.x;
        __shared__ float gf[HH];
        float acc = 0.f;
#pragma unroll
        for (int f = 0; f < FG; ++f) acc += graph[b * FG + f] * Wg[f * HH + h];
        gf[h] = acc;
        __syncthreads();
        float a2 = 0.f;
#pragma unroll 4
        for (int k = 0; k < HH; ++k) a2 += gf[k] * Wmg[k * HH + h];
        mg[b * HH + h] = a2;
    } else {
        // We[f][h] = sum_k W_enc_e[f][k] * W_me[k][h]
#pragma unroll
        for (int f = 0; f < FE; ++f) {
            float acc = 0.f;
#pragma unroll 4
            for (int k = 0; k < HH; ++k) acc += Wee[f * HH + k] * Wme[k * HH + h];
            We[f * HH + h] = acc;
        }
    }
}

// K1: X = [node_fts | hidden] @ [W_m1 | W_m2 | W_o1], node_fts folded on the fly.
// 512 blocks x 256 threads; each block does 8 rows x 384 cols.
__global__ __launch_bounds__(256) void k1_gemm(
    const float* __restrict__ base_node, const float* __restrict__ hidden,
    const float* __restrict__ hints, const float* __restrict__ Wh,
    const float* __restrict__ Wm1, const float* __restrict__ Wm2,
    const float* __restrict__ Wo1, const float* __restrict__ mg,
    float* __restrict__ m1p, float* __restrict__ m2, float* __restrict__ o1,
    int t) {
    __shared__ float z[8][256];
    const int lane = threadIdx.x & 127;
    const int half = threadIdx.x >> 7;   // 0/1 -> rows half*4 .. half*4+3
    const int row0 = blockIdx.x * 8;

    // stage z tile: nf = base + hint @ W_enc_h ; then hidden
#pragma unroll
    for (int r = 0; r < 4; ++r) {
        int rr = half * 4 + r;
        int row = row0 + rr;
        float nf = base_node[row * HH + lane];
        if (t > 0) {
            const float* hr = hints + ((size_t)(t - 1) * BB * NN + row) * FH;
#pragma unroll
            for (int f = 0; f < FH; ++f) nf += hr[f] * Wh[f * HH + lane];
        }
        z[rr][lane] = nf;
        z[rr][128 + lane] = hidden[row * HH + lane];
    }
    __syncthreads();

    float acc[4][3];
#pragma unroll
    for (int r = 0; r < 4; ++r) { acc[r][0] = 0.f; acc[r][1] = 0.f; acc[r][2] = 0.f; }

#pragma unroll 4
    for (int k = 0; k < 256; ++k) {
        float w0 = Wm1[k * HH + lane];
        float w1 = Wm2[k * HH + lane];
        float w2 = Wo1[k * HH + lane];
#pragma unroll
        for (int r = 0; r < 4; ++r) {
            float zv = z[half * 4 + r][k];
            acc[r][0] = fmaf(zv, w0, acc[r][0]);
            acc[r][1] = fmaf(zv, w1, acc[r][1]);
            acc[r][2] = fmaf(zv, w2, acc[r][2]);
        }
    }

#pragma unroll
    for (int r = 0; r < 4; ++r) {
        int row = row0 + half * 4 + r;
        int b = row >> 7;
        m1p[row * HH + lane] = acc[r][0] + mg[b * HH + lane];  // fold msg_g
        m2[row * HH + lane] = acc[r][1];
        o1[row * HH + lane] = acc[r][2];
    }
}

// K2: per (b,i): M[h] = max_{j valid}(m2[b,j,h] + e[b,i,j,h]) with e recomputed
// from raw edge feats (8 FMA); agg = relu(m1p + M) (or -1e9 if no valid j);
// hidden = relu(o1 + agg@W_o2); decoder on last round of each step.
__global__ __launch_bounds__(HH) void k2_max(
    const float* __restrict__ edge, const int* __restrict__ adj,
    const float* __restrict__ We, const float* __restrict__ m1p,
    const float* __restrict__ m2, const float* __restrict__ o1,
    const float* __restrict__ Wo2, const float* __restrict__ Wdn,
    const float* __restrict__ Wde, float* __restrict__ hidden,
    float* __restrict__ out, int t, int last) {
    __shared__ float e_lds[NN][FE];
    __shared__ int adj_lds[NN];
    __shared__ float agg_lds[NN];
    __shared__ float hnew_lds[HH];
    const int h = threadIdx.x;
    const int bi = blockIdx.x;  // b*N + i
    const int b = bi >> 7;

    // stage this receiver's edge row [128 j][8 f] and adjacency row
    const float4* ep = (const float4*)(edge + (size_t)bi * NN * FE);
    float4 e0 = ep[h * 2];
    float4 e1 = ep[h * 2 + 1];
    *(float4*)&e_lds[h][0] = e0;
    *(float4*)&e_lds[h][4] = e1;
    adj_lds[h] = adj[(size_t)bi * NN + h];

    float we[FE];
#pragma unroll
    for (int f = 0; f < FE; ++f) we[f] = We[f * HH + h];
    __syncthreads();

    float M = -3e38f;
    const float* m2b = m2 + (size_t)b * NN * HH;
#pragma unroll 8
    for (int j = 0; j < NN; ++j) {
        float4 ev0 = *(const float4*)&e_lds[j][0];
        float4 ev1 = *(const float4*)&e_lds[j][4];
        float e = ev0.x * we[0] + ev0.y * we[1] + ev0.z * we[2] + ev0.w * we[3] +
                  ev1.x * we[4] + ev1.y * we[5] + ev1.z * we[6] + ev1.w * we[7];
        float v = e + m2b[j * HH + h];
        M = fmaxf(M, adj_lds[j] > 0 ? v : -3e38f);
    }
    // exact semantics: if no valid sender, reference agg = -1e9 (pre-relu'd msgs all masked)
    float agg = (M > -1e37f) ? fmaxf(m1p[bi * HH + h] + M, 0.f) : -1e9f;
    agg_lds[h] = agg;
    __syncthreads();

    float acc = o1[bi * HH + h];
#pragma unroll 4
    for (int k = 0; k < HH; ++k) acc += agg_lds[k] * Wo2[k * HH + h];
    float hv = fmaxf(acc, 0.f);
    hidden[bi * HH + h] = hv;

    if (last) {
        hnew_lds[h] = hv;
        __syncthreads();
        if (h < DEC) {
            float a = 0.f, e2 = 0.f;
#pragma unroll 4
            for (int k = 0; k < HH; ++k) {
                a += hnew_lds[k] * Wdn[k * DEC + h];
                e2 += agg_lds[k] * Wde[k * DEC + h];
            }
            out[(((size_t)t * BB + b) * NN + (bi & 127)) * DEC + h] = a + e2;
        }
    }
}

extern "C" void kernel_launch(void* const* d_in, const int* in_sizes, int n_in,
                              void* d_out, int out_size, void* d_ws, size_t ws_size,
                              hipStream_t stream) {
    const float* node = (const float*)d_in[0];
    const float* edge = (const float*)d_in[1];
    const float* graph = (const float*)d_in[2];
    const float* hints = (const float*)d_in[3];
    const int* adj = (const int*)d_in[4];
    const float* Wn = (const float*)d_in[5];
    const float* Wh = (const float*)d_in[6];
    const float* Wee = (const float*)d_in[7];
    const float* Wg = (const float*)d_in[8];
    const float* Wm1 = (const float*)d_in[9];
    const float* Wm2 = (const float*)d_in[10];
    const float* Wme = (const float*)d_in[11];
    const float* Wmg = (const float*)d_in[12];
    const float* Wo1 = (const float*)d_in[13];
    const float* Wo2 = (const float*)d_in[14];
    const float* Wdn = (const float*)d_in[15];
    const float* Wde = (const float*)d_in[16];

    float* ws = (float*)d_ws;
    float* base_node = ws;
    float* We = ws + 524288;
    float* mg = ws + 525312;
    float* m1p = ws + 529408;
    float* m2 = ws + 1053696;
    float* o1 = ws + 1577984;
    float* hidden = ws + 2102272;
    float* out = (float*)d_out;

    prep1<<<BB * NN, HH, 0, stream>>>(node, Wn, base_node, hidden);
    prep2<<<BB + 1, HH, 0, stream>>>(graph, Wg, Wmg, Wee, Wme, mg, We);

    for (int t = 0; t < TT; ++t) {
        for (int ms = 0; ms < 3; ++ms) {
            k1_gemm<<<BB * NN / 8, 256, 0, stream>>>(base_node, hidden, hints, Wh,
                                                     Wm1, Wm2, Wo1, mg, m1p, m2, o1, t);
            k2_max<<<BB * NN, HH, 0, stream>>>(edge, adj, We, m1p, m2, o1, Wo2,
                                               Wdn, Wde, hidden, out, t,
                                               ms == 2 ? 1 : 0);
        }
    }
}

// Round 2
// 3959.547 us; speedup vs baseline: 1.1864x; 1.1864x over previous
//
#include <hip/hip_runtime.h>
#include <hip/hip_bf16.h>

#define BB 32
#define NN 128
#define TT 16
#define FN 16
#define FE 8
#define FG 8
#define FH 16
#define HH 128
#define DEC 64

// ws layout (floats):
// base_node [4096*128]   @ 0
// We        [8*128]      @ 524288
// mg        [32*128]     @ 525312
// m1p       [4096*128]   @ 529408
// m2        [4096*128]   @ 1053696
// o1        [4096*128]   @ 1577984
// hidden    [4096*128]   @ 2102272
// egather   [4096*128*8] @ 2626560   (compacted valid-edge rows, fp32)
// jlist     [4096*128]   @ 6820864   (int)
// cnt       [4096]       @ 7345152   (int)
// total ~7.35M floats = 29.4 MB

__global__ __launch_bounds__(HH) void prep1(const float* __restrict__ node,
                                            const float* __restrict__ Wn,
                                            float* __restrict__ base_node,
                                            float* __restrict__ hidden) {
    int row = blockIdx.x;
    int h = threadIdx.x;
    float acc = 0.f;
#pragma unroll
    for (int f = 0; f < FN; ++f)
        acc += node[row * FN + f] * Wn[f * HH + h];
    base_node[row * HH + h] = acc;
    hidden[row * HH + h] = 0.f;
}

__global__ __launch_bounds__(HH) void prep2(const float* __restrict__ graph,
                                            const float* __restrict__ Wg,
                                            const float* __restrict__ Wmg,
                                            const float* __restrict__ Wee,
                                            const float* __restrict__ Wme,
                                            float* __restrict__ mg,
                                            float* __restrict__ We) {
    int h = threadIdx.x;
    if (blockIdx.x < BB) {
        int b = blockIdx.x;
        __shared__ float gf[HH];
        float acc = 0.f;
#pragma unroll
        for (int f = 0; f < FG; ++f) acc += graph[b * FG + f] * Wg[f * HH + h];
        gf[h] = acc;
        __syncthreads();
        float a2 = 0.f;
#pragma unroll 4
        for (int k = 0; k < HH; ++k) a2 += gf[k] * Wmg[k * HH + h];
        mg[b * HH + h] = a2;
    } else {
#pragma unroll
        for (int f = 0; f < FE; ++f) {
            float acc = 0.f;
#pragma unroll 4
            for (int k = 0; k < HH; ++k) acc += Wee[f * HH + k] * Wme[k * HH + h];
            We[f * HH + h] = acc;
        }
    }
}

// Compact valid senders per receiver: jlist + gathered edge rows.
__global__ __launch_bounds__(HH) void prep3(const float* __restrict__ edge,
                                            const int* __restrict__ adj,
                                            float* __restrict__ eg,
                                            int* __restrict__ jl,
                                            int* __restrict__ cnt) {
    int bi = blockIdx.x;
    int j = threadIdx.x;
    __shared__ int w0cnt;
    bool valid = adj[(size_t)bi * NN + j] > 0;
    unsigned long long mask = __ballot(valid);
    int lane = j & 63;
    int wave = j >> 6;
    int prefix = __popcll(mask & ((1ull << lane) - 1ull));
    int wcount = __popcll(mask);
    if (wave == 0 && lane == 0) w0cnt = wcount;
    __syncthreads();
    int base = (wave == 1) ? w0cnt : 0;
    if (wave == 1 && lane == 0) cnt[bi] = w0cnt + wcount;
    if (valid) {
        int pos = base + prefix;
        jl[bi * NN + pos] = j;
        const float4* src = (const float4*)(edge + ((size_t)bi * NN + j) * FE);
        float4* dst = (float4*)(eg + ((size_t)bi * NN + pos) * FE);
        dst[0] = src[0];
        dst[1] = src[1];
    }
}

// K1: [node_fts | hidden] @ [W_m1 | W_m2 | W_o1]; z read from LDS via float4.
__global__ __launch_bounds__(256) void k1_gemm(
    const float* __restrict__ base_node, const float* __restrict__ hidden,
    const float* __restrict__ hints, const float* __restrict__ Wh,
    const float* __restrict__ Wm1, const float* __restrict__ Wm2,
    const float* __restrict__ Wo1, const float* __restrict__ mg,
    float* __restrict__ m1p, float* __restrict__ m2, float* __restrict__ o1,
    int t) {
    __shared__ float zs[8][256];
    const int lane = threadIdx.x & 127;
    const int half = threadIdx.x >> 7;
    const int row0 = blockIdx.x * 8;

#pragma unroll
    for (int r = 0; r < 4; ++r) {
        int rr = half * 4 + r;
        int row = row0 + rr;
        float nf = base_node[row * HH + lane];
        if (t > 0) {
            const float* hr = hints + ((size_t)(t - 1) * BB * NN + row) * FH;
#pragma unroll
            for (int f = 0; f < FH; ++f) nf += hr[f] * Wh[f * HH + lane];
        }
        zs[rr][lane] = nf;
        zs[rr][128 + lane] = hidden[row * HH + lane];
    }
    __syncthreads();

    float acc[4][3];
#pragma unroll
    for (int r = 0; r < 4; ++r) { acc[r][0] = 0.f; acc[r][1] = 0.f; acc[r][2] = 0.f; }
    const int h4 = half * 4;

#pragma unroll 4
    for (int kk = 0; kk < 64; ++kk) {
        const int k0 = kk * 4;
        float4 z0 = *(const float4*)&zs[h4 + 0][k0];
        float4 z1 = *(const float4*)&zs[h4 + 1][k0];
        float4 z2 = *(const float4*)&zs[h4 + 2][k0];
        float4 z3 = *(const float4*)&zs[h4 + 3][k0];
#define K1STEP(COMP, KOFF)                                                      \
        {                                                                       \
            float w0 = Wm1[(k0 + KOFF) * HH + lane];                            \
            float w1 = Wm2[(k0 + KOFF) * HH + lane];                            \
            float w2 = Wo1[(k0 + KOFF) * HH + lane];                            \
            acc[0][0] = fmaf(z0.COMP, w0, acc[0][0]);                           \
            acc[0][1] = fmaf(z0.COMP, w1, acc[0][1]);                           \
            acc[0][2] = fmaf(z0.COMP, w2, acc[0][2]);                           \
            acc[1][0] = fmaf(z1.COMP, w0, acc[1][0]);                           \
            acc[1][1] = fmaf(z1.COMP, w1, acc[1][1]);                           \
            acc[1][2] = fmaf(z1.COMP, w2, acc[1][2]);                           \
            acc[2][0] = fmaf(z2.COMP, w0, acc[2][0]);                           \
            acc[2][1] = fmaf(z2.COMP, w1, acc[2][1]);                           \
            acc[2][2] = fmaf(z2.COMP, w2, acc[2][2]);                           \
            acc[3][0] = fmaf(z3.COMP, w0, acc[3][0]);                           \
            acc[3][1] = fmaf(z3.COMP, w1, acc[3][1]);                           \
            acc[3][2] = fmaf(z3.COMP, w2, acc[3][2]);                           \
        }
        K1STEP(x, 0)
        K1STEP(y, 1)
        K1STEP(z, 2)
        K1STEP(w, 3)
#undef K1STEP
    }

#pragma unroll
    for (int r = 0; r < 4; ++r) {
        int row = row0 + h4 + r;
        int b = row >> 7;
        m1p[row * HH + lane] = acc[r][0] + mg[b * HH + lane];
        m2[row * HH + lane] = acc[r][1];
        o1[row * HH + lane] = acc[r][2];
    }
}

// K2: compacted masked-max aggregation + o2-dot + hidden update (+ decoder).
__global__ __launch_bounds__(HH) void k2_max(
    const float* __restrict__ eg, const int* __restrict__ jl,
    const int* __restrict__ cnt, const float* __restrict__ We,
    const float* __restrict__ m1p, const float* __restrict__ m2,
    const float* __restrict__ o1, const float* __restrict__ Wo2,
    const float* __restrict__ Wdn, const float* __restrict__ Wde,
    float* __restrict__ hidden, float* __restrict__ out, int t, int last) {
    __shared__ float agg_lds[HH];
    __shared__ float hnew_lds[HH];
    const int h = threadIdx.x;
    const int bi = blockIdx.x;
    const int b = bi >> 7;

    const float we0 = We[0 * HH + h], we1 = We[1 * HH + h];
    const float we2 = We[2 * HH + h], we3 = We[3 * HH + h];
    const float we4 = We[4 * HH + h], we5 = We[5 * HH + h];
    const float we6 = We[6 * HH + h], we7 = We[7 * HH + h];

    const float* __restrict__ egb = eg + (size_t)bi * NN * FE;
    const int* __restrict__ jlb = jl + bi * NN;
    const float* __restrict__ m2b = m2 + (size_t)b * NN * HH;
    const int c = cnt[bi];

    float M = -3e38f;
#pragma unroll 4
    for (int k = 0; k < c; ++k) {
        const float* er = egb + k * FE;   // uniform address -> scalar/broadcast load
        const int jj = jlb[k];            // uniform
        float e = er[0] * we0;
        e = fmaf(er[1], we1, e);
        e = fmaf(er[2], we2, e);
        e = fmaf(er[3], we3, e);
        e = fmaf(er[4], we4, e);
        e = fmaf(er[5], we5, e);
        e = fmaf(er[6], we6, e);
        e = fmaf(er[7], we7, e);
        M = fmaxf(M, e + m2b[jj * HH + h]);
    }
    float agg = (c > 0) ? fmaxf(m1p[bi * HH + h] + M, 0.f) : -1e9f;
    agg_lds[h] = agg;
    __syncthreads();

    float acc = o1[bi * HH + h];
    const float4* a4 = (const float4*)agg_lds;
#pragma unroll 8
    for (int kk = 0; kk < 32; ++kk) {
        float4 a = a4[kk];
        acc = fmaf(a.x, Wo2[(kk * 4 + 0) * HH + h], acc);
        acc = fmaf(a.y, Wo2[(kk * 4 + 1) * HH + h], acc);
        acc = fmaf(a.z, Wo2[(kk * 4 + 2) * HH + h], acc);
        acc = fmaf(a.w, Wo2[(kk * 4 + 3) * HH + h], acc);
    }
    float hv = fmaxf(acc, 0.f);
    hidden[bi * HH + h] = hv;

    if (last) {
        hnew_lds[h] = hv;
        __syncthreads();
        if (h < DEC) {
            float a = 0.f, e2 = 0.f;
            const float4* h4p = (const float4*)hnew_lds;
#pragma unroll 8
            for (int kk = 0; kk < 32; ++kk) {
                float4 hv4 = h4p[kk];
                float4 av4 = a4[kk];
                a = fmaf(hv4.x, Wdn[(kk * 4 + 0) * DEC + h], a);
                a = fmaf(hv4.y, Wdn[(kk * 4 + 1) * DEC + h], a);
                a = fmaf(hv4.z, Wdn[(kk * 4 + 2) * DEC + h], a);
                a = fmaf(hv4.w, Wdn[(kk * 4 + 3) * DEC + h], a);
                e2 = fmaf(av4.x, Wde[(kk * 4 + 0) * DEC + h], e2);
                e2 = fmaf(av4.y, Wde[(kk * 4 + 1) * DEC + h], e2);
                e2 = fmaf(av4.z, Wde[(kk * 4 + 2) * DEC + h], e2);
                e2 = fmaf(av4.w, Wde[(kk * 4 + 3) * DEC + h], e2);
            }
            out[(((size_t)t * BB + b) * NN + (bi & 127)) * DEC + h] = a + e2;
        }
    }
}

extern "C" void kernel_launch(void* const* d_in, const int* in_sizes, int n_in,
                              void* d_out, int out_size, void* d_ws, size_t ws_size,
                              hipStream_t stream) {
    const float* node = (const float*)d_in[0];
    const float* edge = (const float*)d_in[1];
    const float* graph = (const float*)d_in[2];
    const float* hints = (const float*)d_in[3];
    const int* adj = (const int*)d_in[4];
    const float* Wn = (const float*)d_in[5];
    const float* Wh = (const float*)d_in[6];
    const float* Wee = (const float*)d_in[7];
    const float* Wg = (const float*)d_in[8];
    const float* Wm1 = (const float*)d_in[9];
    const float* Wm2 = (const float*)d_in[10];
    const float* Wme = (const float*)d_in[11];
    const float* Wmg = (const float*)d_in[12];
    const float* Wo1 = (const float*)d_in[13];
    const float* Wo2 = (const float*)d_in[14];
    const float* Wdn = (const float*)d_in[15];
    const float* Wde = (const float*)d_in[16];

    float* ws = (float*)d_ws;
    float* base_node = ws;
    float* We = ws + 524288;
    float* mg = ws + 525312;
    float* m1p = ws + 529408;
    float* m2 = ws + 1053696;
    float* o1 = ws + 1577984;
    float* hidden = ws + 2102272;
    float* eg = ws + 2626560;
    int* jl = (int*)(ws + 6820864);
    int* cnt = (int*)(ws + 7345152);
    float* out = (float*)d_out;

    prep1<<<BB * NN, HH, 0, stream>>>(node, Wn, base_node, hidden);
    prep2<<<BB + 1, HH, 0, stream>>>(graph, Wg, Wmg, Wee, Wme, mg, We);
    prep3<<<BB * NN, HH, 0, stream>>>(edge, adj, eg, jl, cnt);

    for (int t = 0; t < TT; ++t) {
        for (int ms = 0; ms < 3; ++ms) {
            k1_gemm<<<BB * NN / 8, 256, 0, stream>>>(base_node, hidden, hints, Wh,
                                                     Wm1, Wm2, Wo1, mg, m1p, m2, o1, t);
            k2_max<<<BB * NN, HH, 0, stream>>>(eg, jl, cnt, We, m1p, m2, o1, Wo2,
                                               Wdn, Wde, hidden, out, t,
                                               ms == 2 ? 1 : 0);
        }
    }
}